// Round 4
// baseline (151.139 us; speedup 1.0000x reference)
//
#include <hip/hip_runtime.h>
#include <math.h>

#define HW    512
#define IMG   (512 * 512)
#define NB    64
#define SR    8                     // strip rows
#define BLOCK 256
#define WPB   4                     // waves per block
#define SPB   8                     // strips per block (consecutive, same image)
#define NBLOCKS 512                 // exactly 2 blocks/CU, persistent
// LDS layout (floats): pbuf0[10*512] | pbuf1[10*512] | rbuf0[8*512] | rbuf1[8*512]
#define PBUF(c)  ((c) * 5120)
#define RBUF(c)  (10240 + (c) * 4096)

__device__ __forceinline__ void unpack8(const float4& q0, const float4& q1, float* a) {
    a[0] = q0.x; a[1] = q0.y; a[2] = q0.z; a[3] = q0.w;
    a[4] = q1.x; a[5] = q1.y; a[6] = q1.z; a[7] = q1.w;
}

// Async global->LDS, 16B/lane. LDS dest is wave-uniform base; HW scatters lane i
// at base + i*16 (m104). Source is per-lane.
__device__ __forceinline__ void gload_lds16(const float* g, float* l) {
    __builtin_amdgcn_global_load_lds(
        (const __attribute__((address_space(1))) void*)g,
        (__attribute__((address_space(3))) void*)l,
        16, 0, 0);
}

// R0-R3 all landed at 45-47 us regardless of structure (incl. L3-warm runs) --
// never sustaining steady-state MLP: R3 drained vmcnt to 0 per strip and died.
// Here: persistent blocks (2/CU), double-buffered strips, counted vmcnt(9)
// (never 0 mid-loop, T3/T4 pattern) + raw s_barrier. Each wave keeps 9 KB in
// flight continuously.
__global__ __launch_bounds__(BLOCK, 2) void eik_main(const float* __restrict__ pred,
                                                     const float* __restrict__ reach,
                                                     float* __restrict__ partials) {
    const int lane = threadIdx.x & 63;
    const int w    = threadIdx.x >> 6;
    const int b    = blockIdx.x >> 3;            // image (8 blocks per image)
    const int s0   = (blockIdx.x & 7) * SPB;     // first strip (of 64) in image

    const float* pbase = pred  + (size_t)b * IMG;
    const float* rbase = reach + (size_t)b * IMG;

    __shared__ float smem[18432];                // 72 KB
    __shared__ float sv[WPB], sc[WPB];

    // Stage one strip (10 pred rows edge-clamped + 8 reach rows = 36 KB) into
    // buffer c. 36 x 1KB units; wave w takes units u = 4k+w (9 each).
    auto STAGE = [&](int sl, int c) {
        const int y0 = sl * SR;
        float* pb = smem + PBUF(c);
        float* rb = smem + RBUF(c);
#pragma unroll
        for (int k = 0; k < 9; ++k) {
            const int u = (k << 2) | w;
            if (u < 20) {                        // pred rows y0-1 .. y0+8, clamped
                int gr = y0 - 1 + (u >> 1);
                gr = gr < 0 ? 0 : (gr > HW - 1 ? HW - 1 : gr);
                gload_lds16(pbase + (size_t)gr * HW + ((u & 1) << 8) + (lane << 2),
                            pb + u * 256);
            } else {                             // reach rows y0 .. y0+7
                const int v = u - 20;
                gload_lds16(rbase + (size_t)(y0 + (v >> 1)) * HW + ((v & 1) << 8) + (lane << 2),
                            rb + v * 256);
            }
        }
    };

    float vsum = 0.0f, csum = 0.0f;

    STAGE(s0, 0);                                // prologue: strip 0 -> buf0

    for (int s = 0; s < SPB; ++s) {
        const int cur = s & 1;
        if (s + 1 < SPB) {
            STAGE(s0 + s + 1, cur ^ 1);          // 9 new loads -> 18 outstanding
            asm volatile("s_waitcnt vmcnt(9)" ::: "memory");  // strip s landed
        } else {
            asm volatile("s_waitcnt vmcnt(0)" ::: "memory");  // last strip: drain
        }
        __builtin_amdgcn_sched_barrier(0);
        __builtin_amdgcn_s_barrier();            // all waves' strip-s data in LDS
        __builtin_amdgcn_sched_barrier(0);

        const float* pb = smem + PBUF(cur);
        const float* rb = smem + RBUF(cur);

        // wave w computes strip rows 2w, 2w+1: needs pbuf rows 2w..2w+3
        float4 P[4][2], R[2][2];
#pragma unroll
        for (int j = 0; j < 4; ++j) {
            const float* p = pb + (2 * w + j) * HW + (lane << 3);
            P[j][0] = *(const float4*)p;
            P[j][1] = *(const float4*)(p + 4);
        }
#pragma unroll
        for (int t = 0; t < 2; ++t) {
            const float* p = rb + (2 * w + t) * HW + (lane << 3);
            R[t][0] = *(const float4*)p;
            R[t][1] = *(const float4*)(p + 4);
        }

#pragma unroll
        for (int t = 0; t < 2; ++t) {
            float am[8], a0[8], ap[8], rv[8];
            unpack8(P[t][0],     P[t][1],     am);
            unpack8(P[t + 1][0], P[t + 1][1], a0);
            unpack8(P[t + 2][0], P[t + 2][1], ap);
            unpack8(R[t][0],     R[t][1],     rv);

            float sA[8], dA[8];
#pragma unroll
            for (int i = 0; i < 8; ++i) {
                sA[i] = am[i] + 2.0f * a0[i] + ap[i];
                dA[i] = ap[i] - am[i];
            }

            float sl = __shfl_up(sA[7], 1, 64);
            float dl = __shfl_up(dA[7], 1, 64);
            float sr = __shfl_down(sA[0], 1, 64);
            float dr = __shfl_down(dA[0], 1, 64);
            if (lane == 0)  { sl = sA[0]; dl = dA[0]; }
            if (lane == 63) { sr = sA[7]; dr = dA[7]; }

            const float S[10] = {sl, sA[0], sA[1], sA[2], sA[3], sA[4], sA[5], sA[6], sA[7], sr};
            const float D[10] = {dl, dA[0], dA[1], dA[2], dA[3], dA[4], dA[5], dA[6], dA[7], dr};

#pragma unroll
            for (int i = 0; i < 8; ++i) {
                const float gx = (S[i+2] - S[i]) * 0.125f;
                const float gy = (D[i] + 2.0f * D[i+1] + D[i+2]) * 0.125f;
                const float mag  = __builtin_amdgcn_sqrtf(gx * gx + gy * gy + 1e-8f);
                const float viol = fabsf(mag - 1.0f);
                const bool  m    = rv[i] > 0.5f;
                vsum += m ? viol : 0.0f;
                csum += m ? 1.0f : 0.0f;
            }
        }

        __builtin_amdgcn_sched_barrier(0);
        __builtin_amdgcn_s_barrier();            // all waves done reading buf cur
        __builtin_amdgcn_sched_barrier(0);
    }

    // wave reduction, amortized over all 8 strips
#pragma unroll
    for (int off = 32; off > 0; off >>= 1) {
        vsum += __shfl_down(vsum, off, 64);
        csum += __shfl_down(csum, off, 64);
    }
    if (lane == 0) { sv[w] = vsum; sc[w] = csum; }
    __syncthreads();
    if (threadIdx.x == 0) {
        partials[2 * blockIdx.x]     = sv[0] + sv[1] + sv[2] + sv[3];
        partials[2 * blockIdx.x + 1] = sc[0] + sc[1] + sc[2] + sc[3];
    }
}

__global__ __launch_bounds__(BLOCK) void eik_finalize(const float* __restrict__ partials,
                                                      float* __restrict__ out) {
    float v = 0.0f, c = 0.0f;
    for (int i = threadIdx.x; i < NBLOCKS; i += BLOCK) {
        v += partials[2 * i];
        c += partials[2 * i + 1];
    }
#pragma unroll
    for (int off = 32; off > 0; off >>= 1) {
        v += __shfl_down(v, off, 64);
        c += __shfl_down(c, off, 64);
    }
    __shared__ float sv[4], sc[4];
    const int lane = threadIdx.x & 63;
    const int wid  = threadIdx.x >> 6;
    if (lane == 0) { sv[wid] = v; sc[wid] = c; }
    __syncthreads();
    if (threadIdx.x == 0) {
        const float vt = sv[0] + sv[1] + sv[2] + sv[3];
        const float ct = sc[0] + sc[1] + sc[2] + sc[3];
        out[0] = vt / fmaxf(ct, 1.0f);
    }
}

extern "C" void kernel_launch(void* const* d_in, const int* in_sizes, int n_in,
                              void* d_out, int out_size, void* d_ws, size_t ws_size,
                              hipStream_t stream) {
    const float* pred  = (const float*)d_in[0];
    const float* reach = (const float*)d_in[1];
    float* out = (float*)d_out;
    float* ws  = (float*)d_ws;

    eik_main<<<NBLOCKS, BLOCK, 0, stream>>>(pred, reach, ws);
    eik_finalize<<<1, BLOCK, 0, stream>>>(ws, out);
}

// Round 5
// 145.883 us; speedup vs baseline: 1.0360x; 1.0360x over previous
//
#include <hip/hip_runtime.h>
#include <math.h>

#define HW   512
#define IMG  (512 * 512)
#define NB   64
#define T    8                                      // output rows per wave
#define BLOCK 256
#define WAVES_PER_BLOCK (BLOCK / 64)
#define WAVES_PER_IMG (HW / T)                      // 64
#define TOTAL_WAVES (NB * WAVES_PER_IMG)            // 4096
#define NBLOCKS     (TOTAL_WAVES / WAVES_PER_BLOCK) // 1024

__device__ __forceinline__ void unpack8(const float4& q0, const float4& q1, float* a) {
    a[0] = q0.x; a[1] = q0.y; a[2] = q0.z; a[3] = q0.w;
    a[4] = q1.x; a[5] = q1.y; a[6] = q1.z; a[7] = q1.w;
}

// R0-R4 lesson: delivered BW is pinned at ~3.0-3.6 TB/s regardless of MLP
// structure (per-CU fill-rate ceiling; m13's 6.29 TB/s copy is R+W, i.e.
// ~3.15 TB/s read). Only lever left: fewer logical bytes. Rolling register
// window at T=8 reads 10 pred rows per 8 outputs (1.25x) vs T=4's 1.5x:
// 160 MB -> 144 MB. Keep the proven-best structure: VGPR loads, no LDS.
__global__ __launch_bounds__(BLOCK, 4) void eik_main(const float* __restrict__ pred,
                                                     const float* __restrict__ reach,
                                                     float* __restrict__ partials) {
    const int lane = threadIdx.x & 63;
    const int w    = blockIdx.x * WAVES_PER_BLOCK + (threadIdx.x >> 6);
    const int y0   = (w & (WAVES_PER_IMG - 1)) * T;
    const int b    = w / WAVES_PER_IMG;
    const int xo   = lane << 3;

    const float* base  = pred  + (size_t)b * IMG;
    const float* rbase = reach + (size_t)b * IMG;

    // clamped row pointer
    auto rowp = [&](int y) {
        y = y < 0 ? 0 : (y > HW - 1 ? HW - 1 : y);
        return base + (size_t)y * HW + xo;
    };

    // rolling window: am = row y-1, a0 = row y, ap = row y+1
    float4 am0, am1, a00, a01, ap0, ap1;
    {
        const float* p = rowp(y0 - 1);
        am0 = *(const float4*)p; am1 = *(const float4*)(p + 4);
        p = rowp(y0);
        a00 = *(const float4*)p; a01 = *(const float4*)(p + 4);
        p = rowp(y0 + 1);
        ap0 = *(const float4*)p; ap1 = *(const float4*)(p + 4);
    }
    float4 rv0, rv1;
    {
        const float* p = rbase + (size_t)y0 * HW + xo;
        rv0 = *(const float4*)p; rv1 = *(const float4*)(p + 4);
    }

    float vsum = 0.0f, csum = 0.0f;

#pragma unroll
    for (int t = 0; t < T; ++t) {
        // prefetch next step's pred row (y0+t+2) and reach row (y0+t+1)
        // BEFORE computing this step -> depth-1 per-wave pipeline.
        float4 nx0, nx1, rn0, rn1;
        if (t < T - 1) {
            const float* p = rowp(y0 + t + 2);
            nx0 = *(const float4*)p; nx1 = *(const float4*)(p + 4);
            p = rbase + (size_t)(y0 + t + 1) * HW + xo;
            rn0 = *(const float4*)p; rn1 = *(const float4*)(p + 4);
        }

        float am[8], a0[8], ap[8], rv[8];
        unpack8(am0, am1, am);
        unpack8(a00, a01, a0);
        unpack8(ap0, ap1, ap);
        unpack8(rv0, rv1, rv);

        // separable Sobel: S = vertical [1,2,1], D = vertical [-1,0,1]
        float s[8], d[8];
#pragma unroll
        for (int i = 0; i < 8; ++i) {
            s[i] = am[i] + 2.0f * a0[i] + ap[i];
            d[i] = ap[i] - am[i];
        }

        float sl = __shfl_up(s[7], 1, 64);
        float dl = __shfl_up(d[7], 1, 64);
        float sr = __shfl_down(s[0], 1, 64);
        float dr = __shfl_down(d[0], 1, 64);
        if (lane == 0)  { sl = s[0]; dl = d[0]; }
        if (lane == 63) { sr = s[7]; dr = d[7]; }

        const float S[10] = {sl, s[0], s[1], s[2], s[3], s[4], s[5], s[6], s[7], sr};
        const float D[10] = {dl, d[0], d[1], d[2], d[3], d[4], d[5], d[6], d[7], dr};

#pragma unroll
        for (int i = 0; i < 8; ++i) {
            const float gx = (S[i+2] - S[i]) * 0.125f;
            const float gy = (D[i] + 2.0f * D[i+1] + D[i+2]) * 0.125f;
            const float mag  = __builtin_amdgcn_sqrtf(gx * gx + gy * gy + 1e-8f);
            const float viol = fabsf(mag - 1.0f);
            const bool  m    = rv[i] > 0.5f;
            vsum += m ? viol : 0.0f;
            csum += m ? 1.0f : 0.0f;
        }

        // rotate window
        am0 = a00; am1 = a01;
        a00 = ap0; a01 = ap1;
        ap0 = nx0; ap1 = nx1;
        rv0 = rn0; rv1 = rn1;
    }

    // wave-64 reduction (amortized over T rows)
#pragma unroll
    for (int off = 32; off > 0; off >>= 1) {
        vsum += __shfl_down(vsum, off, 64);
        csum += __shfl_down(csum, off, 64);
    }

    __shared__ float sv[WAVES_PER_BLOCK];
    __shared__ float sc[WAVES_PER_BLOCK];
    const int wid = threadIdx.x >> 6;
    if (lane == 0) { sv[wid] = vsum; sc[wid] = csum; }
    __syncthreads();
    if (threadIdx.x == 0) {
        partials[2 * blockIdx.x]     = sv[0] + sv[1] + sv[2] + sv[3];
        partials[2 * blockIdx.x + 1] = sc[0] + sc[1] + sc[2] + sc[3];
    }
}

__global__ __launch_bounds__(BLOCK) void eik_finalize(const float* __restrict__ partials,
                                                      float* __restrict__ out) {
    float v = 0.0f, c = 0.0f;
    for (int i = threadIdx.x; i < NBLOCKS; i += BLOCK) {
        v += partials[2 * i];
        c += partials[2 * i + 1];
    }
#pragma unroll
    for (int off = 32; off > 0; off >>= 1) {
        v += __shfl_down(v, off, 64);
        c += __shfl_down(c, off, 64);
    }
    __shared__ float sv[WAVES_PER_BLOCK];
    __shared__ float sc[WAVES_PER_BLOCK];
    const int lane = threadIdx.x & 63;
    const int wid  = threadIdx.x >> 6;
    if (lane == 0) { sv[wid] = v; sc[wid] = c; }
    __syncthreads();
    if (threadIdx.x == 0) {
        const float vt = sv[0] + sv[1] + sv[2] + sv[3];
        const float ct = sc[0] + sc[1] + sc[2] + sc[3];
        out[0] = vt / fmaxf(ct, 1.0f);
    }
}

extern "C" void kernel_launch(void* const* d_in, const int* in_sizes, int n_in,
                              void* d_out, int out_size, void* d_ws, size_t ws_size,
                              hipStream_t stream) {
    const float* pred  = (const float*)d_in[0];
    const float* reach = (const float*)d_in[1];
    float* out = (float*)d_out;
    float* ws  = (float*)d_ws;

    eik_main<<<NBLOCKS, BLOCK, 0, stream>>>(pred, reach, ws);
    eik_finalize<<<1, BLOCK, 0, stream>>>(ws, out);
}